// Round 10
// baseline (491.386 us; speedup 1.0000x reference)
//
#include <hip/hip_runtime.h>

// Problem constants
#define B_ 4
#define N_ 8192
#define E_ 131072      // 2^17
#define HID_ 128

typedef unsigned short us8 __attribute__((ext_vector_type(8)));
typedef unsigned short us4 __attribute__((ext_vector_type(4)));
typedef unsigned int   ui4 __attribute__((ext_vector_type(4)));
typedef int            i4  __attribute__((ext_vector_type(4)));
typedef __bf16         v8bf __attribute__((ext_vector_type(8)));
typedef _Float16       hf8 __attribute__((ext_vector_type(8)));
typedef float          v4f  __attribute__((ext_vector_type(4)));
typedef float          v2f  __attribute__((ext_vector_type(2)));

#define KEY_INF 0xFF800000u   // sortable-u32 key of +inf

__device__ __forceinline__ float b2f(unsigned short u) {
    return __uint_as_float(((unsigned)u) << 16);
}
__device__ __forceinline__ unsigned short f2b(float f) {
    unsigned x = __float_as_uint(f);
    return (unsigned short)((x + 0x7fffu + ((x >> 16) & 1u)) >> 16);   // RNE
}
__device__ __forceinline__ unsigned short f2h(float f) {   // fp32 -> fp16 bits (RNE)
    union { _Float16 h; unsigned short u; } c; c.h = (_Float16)f; return c.u;
}
// monotonic float -> u32 key (unsigned compare order == float order)
__device__ __forceinline__ unsigned fkey(float f) {
    unsigned b = __float_as_uint(f);
    return (b & 0x80000000u) ? ~b : (b | 0x80000000u);
}
__device__ __forceinline__ float funkey(unsigned k) {
    unsigned b = (k & 0x80000000u) ? (k ^ 0x80000000u) : ~k;
    return __uint_as_float(b);
}

// ---- weight repack helper ----------------------------------------------
// w1n (bf16, for k_node MFMA); w2t (FP16, for k_edge packed-math path)
__device__ __forceinline__ void repack_one(const float* __restrict__ w1, const float* __restrict__ w2,
                                           unsigned short* __restrict__ w1n, unsigned short* __restrict__ w2t,
                                           int F, int KPAD, int gid) {
    int t1 = 256 * KPAD;
    if (gid < t1) {
        int j = gid / KPAD, k = gid - j * KPAD;
        float v = 0.f;
        if (k < F) v = (j < 128) ? w1[k * 128 + j] : w1[(F + k) * 128 + (j - 128)];
        w1n[gid] = f2b(v);
    } else {
        int g = gid - t1;
        if (g < 16384) { int j = g >> 7, k = g & 127; w2t[g] = f2h(w2[k * 128 + j]); }
    }
}

// ---- merged setup: fused hist+scan + agg init + x0 prep + weight repack --
// Hist blocks at bid 0..3 (start first, overlap fill/repack); loads manually
// batched 8-deep before the LDS atomics that consume them (R8 fix, verified:
// 289->279.6us). Hist blocks touch ONLY ei/cnt.
__global__ void k_setup(const int* __restrict__ nf, unsigned short* __restrict__ x0b,
                        unsigned* __restrict__ cnt, unsigned* __restrict__ agg,
                        const int* __restrict__ ei,
                        const float* __restrict__ w1a, const float* __restrict__ w2a,
                        const float* __restrict__ w1b, const float* __restrict__ w2b,
                        const float* __restrict__ w1c, const float* __restrict__ w2c,
                        unsigned short* __restrict__ w1n0, unsigned short* __restrict__ w2t0,
                        unsigned short* __restrict__ w1n1, unsigned short* __restrict__ w2t1,
                        unsigned short* __restrict__ w1n2, unsigned short* __restrict__ w2t2) {
    __shared__ unsigned hsh[8192];   // per-batch histogram (32 KB)
    __shared__ unsigned hsw[4];      // wave partial sums
    const int bid = blockIdx.x, tid = threadIdx.x;
    if (bid < 4) {       // fused per-batch histogram + exclusive scan: 4 blocks, FIRST
        const int hb = bid;
        for (int i = tid; i < 8192; i += 256) hsh[i] = 0u;
        __syncthreads();
        const i4* dp = (const i4*)(ei + (hb << 18) + E_);
        for (int k = 0; k < 16; k++) {
            i4 d0 = dp[(k * 8 + 0) * 256 + tid];
            i4 d1 = dp[(k * 8 + 1) * 256 + tid];
            i4 d2 = dp[(k * 8 + 2) * 256 + tid];
            i4 d3 = dp[(k * 8 + 3) * 256 + tid];
            i4 d4 = dp[(k * 8 + 4) * 256 + tid];
            i4 d5 = dp[(k * 8 + 5) * 256 + tid];
            i4 d6 = dp[(k * 8 + 6) * 256 + tid];
            i4 d7 = dp[(k * 8 + 7) * 256 + tid];
            atomicAdd(&hsh[d0[0]], 1u); atomicAdd(&hsh[d0[1]], 1u);
            atomicAdd(&hsh[d0[2]], 1u); atomicAdd(&hsh[d0[3]], 1u);
            atomicAdd(&hsh[d1[0]], 1u); atomicAdd(&hsh[d1[1]], 1u);
            atomicAdd(&hsh[d1[2]], 1u); atomicAdd(&hsh[d1[3]], 1u);
            atomicAdd(&hsh[d2[0]], 1u); atomicAdd(&hsh[d2[1]], 1u);
            atomicAdd(&hsh[d2[2]], 1u); atomicAdd(&hsh[d2[3]], 1u);
            atomicAdd(&hsh[d3[0]], 1u); atomicAdd(&hsh[d3[1]], 1u);
            atomicAdd(&hsh[d3[2]], 1u); atomicAdd(&hsh[d3[3]], 1u);
            atomicAdd(&hsh[d4[0]], 1u); atomicAdd(&hsh[d4[1]], 1u);
            atomicAdd(&hsh[d4[2]], 1u); atomicAdd(&hsh[d4[3]], 1u);
            atomicAdd(&hsh[d5[0]], 1u); atomicAdd(&hsh[d5[1]], 1u);
            atomicAdd(&hsh[d5[2]], 1u); atomicAdd(&hsh[d5[3]], 1u);
            atomicAdd(&hsh[d6[0]], 1u); atomicAdd(&hsh[d6[1]], 1u);
            atomicAdd(&hsh[d6[2]], 1u); atomicAdd(&hsh[d6[3]], 1u);
            atomicAdd(&hsh[d7[0]], 1u); atomicAdd(&hsh[d7[1]], 1u);
            atomicAdd(&hsh[d7[2]], 1u); atomicAdd(&hsh[d7[3]], 1u);
        }
        __syncthreads();
        // thread t owns counters [t*32, t*32+32)
        unsigned loc[32]; unsigned s = 0;
#pragma unroll
        for (int i = 0; i < 8; i++) {
            ui4 v = *(ui4*)&hsh[tid * 32 + i * 4];
            loc[i * 4] = v[0]; loc[i * 4 + 1] = v[1];
            loc[i * 4 + 2] = v[2]; loc[i * 4 + 3] = v[3];
            s += v[0] + v[1] + v[2] + v[3];
        }
        unsigned incl = s;                          // wave-inclusive scan
#pragma unroll
        for (int off = 1; off < 64; off <<= 1) {
            unsigned v = __shfl_up(incl, off);
            if ((tid & 63) >= (unsigned)off) incl += v;
        }
        if ((tid & 63) == 63) hsw[tid >> 6] = incl;
        __syncthreads();
        unsigned wp = 0;
        for (int w = 0; w < (tid >> 6); w++) wp += hsw[w];
        unsigned run = wp + incl - s;               // exclusive over all threads
        unsigned* c = cnt + (hb << 13) + tid * 32;
#pragma unroll
        for (int i = 0; i < 8; i++) {
            ui4 o;
            o[0] = run; run += loc[i * 4];
            o[1] = run; run += loc[i * 4 + 1];
            o[2] = run; run += loc[i * 4 + 2];
            o[3] = run; run += loc[i * 4 + 3];
            *(ui4*)&c[i * 4] = o;
        }
        return;
    }
    if (bid >= 4100) {   // weight repack tail: 480 blocks
        const int rb = bid - 4100;
        const int gid = rb * 256 + tid;
        if (rb < 96)       repack_one(w1a, w2a, w1n0, w2t0, 16, 32, gid);
        else if (rb < 288) repack_one(w1b, w2b, w1n1, w2t1, 128, 128, gid - 96 * 256);
        else               repack_one(w1c, w2c, w1n2, w2t2, 128, 128, gid - 288 * 256);
        return;
    }
    const int gid = (bid - 4) * 256 + tid;
    ui4 v = {KEY_INF, KEY_INF, KEY_INF, KEY_INF};
    ((ui4*)agg)[gid] = v;                               // 4096 blocks x 256
    if (bid < 516) {                                    // x0 prep: 131072 threads
        i4 x = ((const i4*)nf)[gid];
        us4 o;
        o[0] = f2b((float)x[0]); o[1] = f2b((float)x[1]);
        o[2] = f2b((float)x[2]); o[3] = f2b((float)x[3]);
        ((us4*)x0b)[gid] = o;
    }
}

// ---- per-node projection body: [Yd|Ys] = x @ [W1a|W1b] (+b1 on Yd half) ----
template<int KPAD, bool FROM_AGG>
__device__ __forceinline__ void node_body(
    int bid,
    const unsigned short* __restrict__ xin,
    unsigned* __restrict__ agg,
    const unsigned short* __restrict__ w1n,
    const float* __restrict__ bias1,
    unsigned short* __restrict__ Yd,
    unsigned short* __restrict__ Ys,
    char* smem)
{
    constexpr int ASTR = KPAD + 8;
    unsigned short* A  = (unsigned short*)smem;                       // 64*ASTR
    unsigned short* Yb = (unsigned short*)(smem + 64 * ASTR * 2);     // 64*264

    const int tid = threadIdx.x;
    const int wave = tid >> 6, lane = tid & 63, lq = lane >> 4, lm = lane & 15;
    const int tile = (bid & 7) * 64 + (bid >> 3);   // XCD-affine
    const int n0 = tile * 64;

    v8bf wf[4][KPAD / 32]; float b1v[4];
#pragma unroll
    for (int nt = 0; nt < 4; nt++) {
        const int col = wave * 64 + nt * 16 + lm;
#pragma unroll
        for (int ks = 0; ks < KPAD / 32; ks++)
            wf[nt][ks] = *(const v8bf*)&w1n[col * KPAD + ks * 32 + lq * 8];
        b1v[nt] = (col < 128) ? bias1[col] : 0.f;
    }

    // stage A (64 rows x KPAD)
    {
        const int row = tid >> 2, p = tid & 3;
        if (FROM_AGG) {
#pragma unroll
            for (int i = 0; i < 8; i++) {
                const int c = p + 4 * i;      // 32 ui4 chunks of 4 cols
                unsigned* ap = agg + ((size_t)(n0 + row)) * 128 + c * 4;
                ui4 k = *(ui4*)ap;
                ui4 inf = {KEY_INF, KEY_INF, KEY_INF, KEY_INF};
                *(ui4*)ap = inf;              // re-arm for next layer's atomics
                us4 o;
#pragma unroll
                for (int j = 0; j < 4; j++) {
                    float v = (k[j] == KEY_INF) ? 0.f : funkey(k[j]);
                    v = (v > 0.f) ? v : 0.01f * v;
                    o[j] = f2b(v);
                }
                *(us4*)&A[row * ASTR + c * 4] = o;
            }
        } else {
            us4 v = *(const us4*)(xin + ((size_t)(n0 + row)) * 16 + p * 4);
            *(us4*)&A[row * ASTR + p * 4] = v;
            us4 z = {0, 0, 0, 0};
            *(us4*)&A[row * ASTR + 16 + p * 4] = z;   // zero-pad K 16->32
        }
    }
    __syncthreads();

#pragma unroll
    for (int mt = 0; mt < 4; mt++) {
        v4f acc[4];
#pragma unroll
        for (int nt = 0; nt < 4; nt++) acc[nt] = v4f{0.f, 0.f, 0.f, 0.f};
#pragma unroll
        for (int ks = 0; ks < KPAD / 32; ks++) {
            v8bf a = *(const v8bf*)&A[(mt * 16 + lm) * ASTR + ks * 32 + lq * 8];
#pragma unroll
            for (int nt = 0; nt < 4; nt++)
                acc[nt] = __builtin_amdgcn_mfma_f32_16x16x32_bf16(a, wf[nt][ks], acc[nt], 0, 0, 0);
        }
#pragma unroll
        for (int nt = 0; nt < 4; nt++) {
            const int col = wave * 64 + nt * 16 + lm;
#pragma unroll
            for (int r = 0; r < 4; r++)
                Yb[(mt * 16 + lq * 4 + r) * 264 + col] = f2h(acc[nt][r] + b1v[nt]);
        }
    }
    __syncthreads();

    // coalesced copy-out
    const int bb = tile >> 7, nl0 = (tile & 127) * 64;
#pragma unroll
    for (int i = 0; i < 8; i++) {
        const int idx = tid + 256 * i;          // 2048 us8 chunks
        const int row = idx >> 5, c = idx & 31;
        us8 v = *(const us8*)&Yb[row * 264 + c * 8];
        const int col0 = c * 8;
        unsigned short* dp = (col0 < 128)
            ? (Yd + ((size_t)(bb * N_) + nl0 + row) * 128 + col0)
            : (Ys + ((size_t)(bb * N_) + nl0 + row) * 128 + (col0 - 128));
        *(us8*)dp = v;
    }
}

// conv2/3 node kernel
template<int KPAD>
__global__ __launch_bounds__(256, 3) void k_node(
    const unsigned short* __restrict__ xin, unsigned* __restrict__ agg,
    const unsigned short* __restrict__ w1n, const float* __restrict__ bias1,
    unsigned short* __restrict__ Yd, unsigned short* __restrict__ Ys)
{
    __shared__ __align__(16) char smem[64 * (KPAD + 8) * 2 + 64 * 264 * 2];
    node_body<KPAD, true>(blockIdx.x, xin, agg, w1n, bias1, Yd, Ys, smem);
}

// fused: blocks [0,2048) = edge scatter; [2048,2560) = conv1 node proj
// Scatter materializes the SORTED edge tuple esrt[pos] = {src,dst,ea_bits,0}
// so k_edge needs no random index loads (R9; FETCH 29->17.8MB verified).
__global__ __launch_bounds__(256, 3) void k_scat_node1(
    const int* __restrict__ ei, const float* __restrict__ eaf,
    unsigned* __restrict__ wptr, i4* __restrict__ esrt,
    const unsigned short* __restrict__ x0b,
    const unsigned short* __restrict__ w1n, const float* __restrict__ bias1,
    unsigned short* __restrict__ Yd, unsigned short* __restrict__ Ys)
{
    __shared__ __align__(16) char smem[64 * 40 * 2 + 64 * 264 * 2];
    const int bid = blockIdx.x;
    if (bid < 2048) {   // scatter
        int gid = bid * 256 + threadIdx.x;              // B*E threads
        int b = gid >> 17, e = gid & (E_ - 1);
        int dst = ei[(b << 18) + E_ + e];
        unsigned pos = atomicAdd(&wptr[(b << 13) + dst], 1u);
        int src = ei[(b << 18) + e];
        float ea = eaf[(b << 17) + e];
        i4 t; t[0] = src; t[1] = dst; t[2] = __float_as_int(ea); t[3] = 0;
        esrt[(b << 17) + pos] = t;
        return;
    }
    node_body<32, false>(bid - 2048, x0b, (unsigned*)nullptr, w1n, bias1, Yd, Ys, smem);
}

// ---- fused edge kernel: 512-thread / full-occupancy revision ------------
// gather Yd[dst]+Ys[src]+ea*wea -> leaky -> Hs (fp16, XOR-swizzled) ->
// GEMM2 f16 MFMA -> carried register segmented min -> agg.
//
// R10: same 1024-block grid, same 512-edge chunk per block (per-CU chunk
// footprint IDENTICAL to R8/R9 — the L2-locality optimum is preserved),
// but 512 threads/block: waves/CU 16->32 (full occupancy). R9 proved
// k_edge is NOT fetch-bound (FETCH 29->17.8MB, dur unchanged); R2's
// occupancy attempt failed because it multiplied CHUNKS per CU, not waves.
// This doubles waves per chunk: gather = 8 thr/edge (2 chunks each, shorter
// chains), GEMM = 8 waves x 16 cols (1 col/lane), segmin 1 col/thread.
// Total MFMA, LDS layout, barriers, run-major segmin map: unchanged.
//
// LAYOUT INVARIANT (R5 lesson): carried segmin + interior plain stores
// requires each thread's edge walk to be CONTIGUOUS in sorted order
// (run-major map: Hs row mt*16+lq*4+r of tile jj <-> chunk-edge
// lq*128 + jj*16 + mt*4 + r). Change layout and policy together or not
// at all.
__global__ __launch_bounds__(512, 8) void k_edge(
    const unsigned short* __restrict__ Yd,    // fp16
    const unsigned short* __restrict__ Ys,    // fp16
    const i4* __restrict__ esrt,              // sorted {src,dst,ea_bits,0}
    const unsigned short* __restrict__ w2t,   // [128][128] fp16
    const float* __restrict__ weap,           // [128] = W1 row 2F (fp32)
    const float* __restrict__ bias2,
    unsigned* __restrict__ agg)
{
    __shared__ __align__(16) unsigned short Hs[2][64 * 128];   // fp16, swizzled
    __shared__ __align__(16) int      dstl[2][64];

    const int tid = threadIdx.x;
    const int wave = tid >> 6, lane = tid & 63, lq = lane >> 4, lm = lane & 15;

    // B frags: this wave owns 16 output cols; 1 col per lane
    const int col = wave * 16 + lm;
    hf8 w2f[4];
#pragma unroll
    for (int ks = 0; ks < 4; ks++)
        w2f[ks] = *(const hf8*)&w2t[col * 128 + ks * 32 + lq * 8];
    const float b2v = bias2[col];

    // gather role: 8 threads/edge; arow = Hs row (0..63).
    // Run-major map: Hs row (mt*16 + lq*4 + r) holds chunk-edge
    // lq*128 + jj*16 + mt*4 + r  (contiguous 128-edge run per lq).
    const int arow = tid >> 3, p = tid & 7;
    const int lqg = (arow >> 2) & 3, mtg = arow >> 4, rg = arow & 3;
    const int sl  = lqg * 16 + mtg * 4 + rg;         // dstl slot
    const int se0 = lqg * 128 + mtg * 4 + rg;        // chunk-edge offset (+ jj*16)
    const int rsw = arow & 15;                       // store-side swizzle key

    // weal hoist: this thread's 2 loop-invariant W1-edge chunks (c = p, p+8)
    hf8 wl0, wl1;
    {
        const float* wp = weap + p * 8;
#pragma unroll
        for (int u = 0; u < 8; u++) {
            wl0[u] = (_Float16)wp[u];
            wl1[u] = (_Float16)wp[64 + u];
        }
    }

    __syncthreads();   // prologue ordering margin (cheap, once per block)

    // one block = one chunk of 512 contiguous dst-sorted edges.
    // XCD-affine: XCD x gets 128 consecutive chunks (contiguous dst window).
    const int chunk = (blockIdx.x & 7) * 128 + (blockIdx.x >> 3);
    const int b = chunk >> 8;                        // 256 chunks per batch
    const i4* ebp = esrt + (b << 17) + (chunk & 255) * 512;

    const hf8 c01v = {(_Float16)0.01f, (_Float16)0.01f, (_Float16)0.01f, (_Float16)0.01f,
                      (_Float16)0.01f, (_Float16)0.01f, (_Float16)0.01f, (_Float16)0.01f};

    i4 t = ebp[se0];
    int src = t[0], dst = t[1]; float ea = __int_as_float(t[2]);

    // prologue: gather tile 0 into buf 0 (2 chunks per thread)
    {
        const hf8* ydp = (const hf8*)(Yd + ((size_t)(b * N_) + dst) * 128);
        const hf8* ysp = (const hf8*)(Ys + ((size_t)(b * N_) + src) * 128);
        if (p == 0) dstl[0][sl] = dst;
        const _Float16 eh = (_Float16)ea;
        const hf8 ea8 = {eh, eh, eh, eh, eh, eh, eh, eh};
        hf8 z;
        z = ydp[p] + ysp[p] + wl0 * ea8;
        z = __builtin_elementwise_max(z, z * c01v);   // leaky, v_pk_max_f16
        *(hf8*)&Hs[0][arow * 128 + ((p ^ rsw) * 8)] = z;
        z = ydp[p + 8] + ysp[p + 8] + wl1 * ea8;
        z = __builtin_elementwise_max(z, z * c01v);
        *(hf8*)&Hs[0][arow * 128 + (((p + 8) ^ rsw) * 8)] = z;
    }
    __syncthreads();

    // carried segmented-min state (1 col/thread; run = 128 edges per lq)
    unsigned* aggb = agg + (size_t)(b * N_) * 128;
    float cur0 = 0.f; int curd = -1; bool fseg = true;

    for (int jj = 0; jj < 8; jj++) {
        const int buf = jj & 1;

        // ---- prefetch tuple for tile jj+1 (drains under GEMM2) ----
        if (jj < 7) {
            t = ebp[se0 + (jj + 1) * 16];
            src = t[0]; dst = t[1]; ea = __int_as_float(t[2]);
        }

        // ---- GEMM2 (bias in acc init) + carried register segmented min ----
        {
#pragma unroll
            for (int mt = 0; mt < 4; mt++) {
                const int row = mt * 16 + lm;             // row & 15 == lm
                v4f acc0 = {b2v, b2v, b2v, b2v};
#pragma unroll
                for (int ks = 0; ks < 4; ks++) {
                    hf8 a = *(const hf8*)&Hs[buf][row * 128 + (((ks * 4 + lq) ^ lm) * 8)];
                    acc0 = __builtin_amdgcn_mfma_f32_16x16x32_f16(a, w2f[ks], acc0, 0, 0, 0);
                }
                i4 dv = *(const i4*)&dstl[buf][lq * 16 + mt * 4];
#pragma unroll
                for (int r = 0; r < 4; r++) {
                    const float v0 = acc0[r];
                    const int d = dv[r];
                    if (d != curd) {
                        if (curd >= 0) {
                            unsigned* p0 = aggb + (size_t)curd * 128 + col;
                            if (fseg) {                    // may span into prev run
                                atomicMin(p0, fkey(cur0));
                            } else {                       // interior: exclusive owner
                                *p0 = fkey(cur0);
                            }
                            fseg = false;
                        }
                        curd = d; cur0 = v0;
                    } else {
                        cur0 = fminf(cur0, v0);
                    }
                }
            }
        }

        // ---- gather tile jj+1 into the other buffer ----
        if (jj < 7) {
            const hf8* ydp = (const hf8*)(Yd + ((size_t)(b * N_) + dst) * 128);
            const hf8* ysp = (const hf8*)(Ys + ((size_t)(b * N_) + src) * 128);
            if (p == 0) dstl[buf ^ 1][sl] = dst;
            const _Float16 eh = (_Float16)ea;
            const hf8 ea8 = {eh, eh, eh, eh, eh, eh, eh, eh};
            hf8 z;
            z = ydp[p] + ysp[p] + wl0 * ea8;
            z = __builtin_elementwise_max(z, z * c01v);
            *(hf8*)&Hs[buf ^ 1][arow * 128 + ((p ^ rsw) * 8)] = z;
            z = ydp[p + 8] + ysp[p + 8] + wl1 * ea8;
            z = __builtin_elementwise_max(z, z * c01v);
            *(hf8*)&Hs[buf ^ 1][arow * 128 + (((p + 8) ^ rsw) * 8)] = z;
        }
        __syncthreads();
    }

    // tail flush: touches run end -> may continue in next run/chunk: atomic
    atomicMin(aggb + (size_t)curd * 128 + col, fkey(cur0));
}

// ---- head: out = softplus([x0 | leaky(unkey(agg))] @ lin_w + lin_b) ----
__global__ __launch_bounds__(256, 4) void k_final(
    const unsigned short* __restrict__ x0b, const unsigned* __restrict__ agg,
    const float* __restrict__ lw, const float* __restrict__ lb,
    float* __restrict__ out) {
    __shared__ float w[144 * 8];
    __shared__ float bias8[8];
    __shared__ float xs[64 * 129];    // +1 pad: node-major, bank-spread
    const int tid = threadIdx.x;
    for (int i = tid; i < 1152; i += 256) w[i] = lw[i];
    if (tid < 8) bias8[tid] = lb[tid];
    const int n0 = blockIdx.x * 64;
#pragma unroll
    for (int i = 0; i < 8; i++) {
        const int idx = tid + 256 * i;
        const int row = idx >> 5, c = idx & 31;
        ui4 k = ((const ui4*)(agg + ((size_t)(n0 + row)) * 128))[c];
#pragma unroll
        for (int j = 0; j < 4; j++) {
            float v = (k[j] == KEY_INF) ? 0.f : funkey(k[j]);
            v = fmaxf(v, 0.01f * v);
            xs[row * 129 + c * 4 + j] = v;
        }
    }
    __syncthreads();
    const int node = tid >> 2, ap = (tid & 3) * 2;   // outputs ap, ap+1
    float a0 = bias8[ap], a1 = bias8[ap + 1];
    const unsigned short* x0 = x0b + (size_t)(n0 + node) * 16;
#pragma unroll
    for (int f = 0; f < 16; f++) {
        const float xv = b2f(x0[f]);
        a0 += xv * w[f * 8 + ap]; a1 += xv * w[f * 8 + ap + 1];
    }
    const float* xr = &xs[node * 129];
#pragma unroll 8
    for (int f = 0; f < 128; f++) {
        const float xv = xr[f];
        a0 += xv * w[(16 + f) * 8 + ap]; a1 += xv * w[(16 + f) * 8 + ap + 1];
    }
    v2f o;
    o[0] = fmaxf(a0, 0.f) + log1pf(expf(-fabsf(a0)));   // stable softplus
    o[1] = fmaxf(a1, 0.f) + log1pf(expf(-fabsf(a1)));
    *(v2f*)&out[(size_t)(n0 + node) * 8 + ap] = o;
}

extern "C" void kernel_launch(void* const* d_in, const int* in_sizes, int n_in,
                              void* d_out, int out_size, void* d_ws, size_t ws_size,
                              hipStream_t stream) {
    (void)in_sizes; (void)n_in; (void)out_size; (void)ws_size;
    const int* nf  = (const int*)d_in[0];
    const int* ei  = (const int*)d_in[1];
    const float* eaf = (const float*)d_in[2];
    const float* cw1[3] = {(const float*)d_in[3],  (const float*)d_in[7],  (const float*)d_in[11]};
    const float* cb1[3] = {(const float*)d_in[4],  (const float*)d_in[8],  (const float*)d_in[12]};
    const float* cw2[3] = {(const float*)d_in[5],  (const float*)d_in[9],  (const float*)d_in[13]};
    const float* cb2[3] = {(const float*)d_in[6],  (const float*)d_in[10], (const float*)d_in[14]};
    const float* lw = (const float*)d_in[15];
    const float* lb = (const float*)d_in[16];
    float* out = (float*)d_out;

    // workspace carve (all 256B aligned) — ~43.6 MB total
    size_t off = 0;
    auto carve = [&](size_t bytes) { void* p = (char*)d_ws + off; off += (bytes + 255) & ~(size_t)255; return p; };
    unsigned short* x0b  = (unsigned short*)carve((size_t)B_ * N_ * 16 * 2);    // 1 MB
    unsigned*       agg  = (unsigned*)carve((size_t)B_ * N_ * 128 * 4);         // 16.8 MB
    unsigned*       cnt  = (unsigned*)carve((size_t)B_ * N_ * 4);               // 128 KB
    i4*             esrt = (i4*)carve((size_t)B_ * E_ * 16);                    // 8.4 MB sorted tuples
    unsigned short* Yd   = (unsigned short*)carve((size_t)B_ * N_ * 128 * 2);   // 8.4 MB (fp16)
    unsigned short* Ys   = (unsigned short*)carve((size_t)B_ * N_ * 128 * 2);   // 8.4 MB (fp16)
    unsigned short* w1n0 = (unsigned short*)carve(256 * 32 * 2);
    unsigned short* w2t0 = (unsigned short*)carve(128 * 128 * 2);
    unsigned short* w1n1 = (unsigned short*)carve(256 * 128 * 2);
    unsigned short* w2t1 = (unsigned short*)carve(128 * 128 * 2);
    unsigned short* w1n2 = (unsigned short*)carve(256 * 128 * 2);
    unsigned short* w2t2 = (unsigned short*)carve(128 * 128 * 2);

    // setup: fused per-batch hist+scan at bid 0..3 (start first, overlap fill)
    k_setup<<<4580, 256, 0, stream>>>(nf, x0b, cnt, agg, ei,
                                      cw1[0], cw2[0], cw1[1], cw2[1], cw1[2], cw2[2],
                                      w1n0, w2t0, w1n1, w2t1, w1n2, w2t2);

    // fused: edge scatter -> esrt tuples (2048 blocks) + conv1 node proj (512)
    k_scat_node1<<<2560, 256, 0, stream>>>(ei, eaf, cnt, esrt, x0b, w1n0, cb1[0], Yd, Ys);
    k_edge<<<1024, 512, 0, stream>>>(Yd, Ys, esrt, w2t0, cw1[0] + 32 * 128, cb2[0], agg);

    // conv2: k_node reads conv1 agg + re-arms it
    k_node<128><<<512, 256, 0, stream>>>(x0b, agg, w1n1, cb1[1], Yd, Ys);
    k_edge<<<1024, 512, 0, stream>>>(Yd, Ys, esrt, w2t1, cw1[1] + 256 * 128, cb2[1], agg);

    // conv3
    k_node<128><<<512, 256, 0, stream>>>(x0b, agg, w1n2, cb1[2], Yd, Ys);
    k_edge<<<1024, 512, 0, stream>>>(Yd, Ys, esrt, w2t2, cw1[2] + 256 * 128, cb2[2], agg);

    k_final<<<512, 256, 0, stream>>>(x0b, agg, lw, lb, out);
}

// Round 11
// 277.776 us; speedup vs baseline: 1.7690x; 1.7690x over previous
//
#include <hip/hip_runtime.h>

// Problem constants
#define B_ 4
#define N_ 8192
#define E_ 131072      // 2^17
#define HID_ 128

typedef unsigned short us8 __attribute__((ext_vector_type(8)));
typedef unsigned short us4 __attribute__((ext_vector_type(4)));
typedef unsigned int   ui4 __attribute__((ext_vector_type(4)));
typedef int            i4  __attribute__((ext_vector_type(4)));
typedef __bf16         v8bf __attribute__((ext_vector_type(8)));
typedef _Float16       hf8 __attribute__((ext_vector_type(8)));
typedef float          v4f  __attribute__((ext_vector_type(4)));
typedef float          v2f  __attribute__((ext_vector_type(2)));

#define KEY_INF 0xFF800000u   // sortable-u32 key of +inf

__device__ __forceinline__ float b2f(unsigned short u) {
    return __uint_as_float(((unsigned)u) << 16);
}
__device__ __forceinline__ unsigned short f2b(float f) {
    unsigned x = __float_as_uint(f);
    return (unsigned short)((x + 0x7fffu + ((x >> 16) & 1u)) >> 16);   // RNE
}
__device__ __forceinline__ unsigned short f2h(float f) {   // fp32 -> fp16 bits (RNE)
    union { _Float16 h; unsigned short u; } c; c.h = (_Float16)f; return c.u;
}
// monotonic float -> u32 key (unsigned compare order == float order)
__device__ __forceinline__ unsigned fkey(float f) {
    unsigned b = __float_as_uint(f);
    return (b & 0x80000000u) ? ~b : (b | 0x80000000u);
}
__device__ __forceinline__ float funkey(unsigned k) {
    unsigned b = (k & 0x80000000u) ? (k ^ 0x80000000u) : ~k;
    return __uint_as_float(b);
}

// ---- weight repack helper ----------------------------------------------
// w1n (bf16, for k_node MFMA); w2t (FP16, for k_edge packed-math path)
__device__ __forceinline__ void repack_one(const float* __restrict__ w1, const float* __restrict__ w2,
                                           unsigned short* __restrict__ w1n, unsigned short* __restrict__ w2t,
                                           int F, int KPAD, int gid) {
    int t1 = 256 * KPAD;
    if (gid < t1) {
        int j = gid / KPAD, k = gid - j * KPAD;
        float v = 0.f;
        if (k < F) v = (j < 128) ? w1[k * 128 + j] : w1[(F + k) * 128 + (j - 128)];
        w1n[gid] = f2b(v);
    } else {
        int g = gid - t1;
        if (g < 16384) { int j = g >> 7, k = g & 127; w2t[g] = f2h(w2[k * 128 + j]); }
    }
}

// ---- merged setup: fused hist+scan + agg init + x0 prep + weight repack --
// R8 config (verified best, 279.6us): hist blocks at bid 0..3 (start first,
// overlap fill/repack); loads manually batched 8-deep before the LDS atomics
// that consume them. Hist blocks touch ONLY ei/cnt.
// R10 lesson: XCD-affine maps are calibrated to block SHAPE — 512-thread
// k_edge blocks broke the (bid&7) XCD heuristic (FETCH 18->270MB). Keep
// 256-thread blocks everywhere the (bid&7) map is used.
__global__ void k_setup(const int* __restrict__ nf, unsigned short* __restrict__ x0b,
                        unsigned* __restrict__ cnt, unsigned* __restrict__ agg,
                        const int* __restrict__ ei,
                        const float* __restrict__ w1a, const float* __restrict__ w2a,
                        const float* __restrict__ w1b, const float* __restrict__ w2b,
                        const float* __restrict__ w1c, const float* __restrict__ w2c,
                        unsigned short* __restrict__ w1n0, unsigned short* __restrict__ w2t0,
                        unsigned short* __restrict__ w1n1, unsigned short* __restrict__ w2t1,
                        unsigned short* __restrict__ w1n2, unsigned short* __restrict__ w2t2) {
    __shared__ unsigned hsh[8192];   // per-batch histogram (32 KB)
    __shared__ unsigned hsw[4];      // wave partial sums
    const int bid = blockIdx.x, tid = threadIdx.x;
    if (bid < 4) {       // fused per-batch histogram + exclusive scan: 4 blocks, FIRST
        const int hb = bid;
        for (int i = tid; i < 8192; i += 256) hsh[i] = 0u;
        __syncthreads();
        const i4* dp = (const i4*)(ei + (hb << 18) + E_);
        for (int k = 0; k < 16; k++) {
            i4 d0 = dp[(k * 8 + 0) * 256 + tid];
            i4 d1 = dp[(k * 8 + 1) * 256 + tid];
            i4 d2 = dp[(k * 8 + 2) * 256 + tid];
            i4 d3 = dp[(k * 8 + 3) * 256 + tid];
            i4 d4 = dp[(k * 8 + 4) * 256 + tid];
            i4 d5 = dp[(k * 8 + 5) * 256 + tid];
            i4 d6 = dp[(k * 8 + 6) * 256 + tid];
            i4 d7 = dp[(k * 8 + 7) * 256 + tid];
            atomicAdd(&hsh[d0[0]], 1u); atomicAdd(&hsh[d0[1]], 1u);
            atomicAdd(&hsh[d0[2]], 1u); atomicAdd(&hsh[d0[3]], 1u);
            atomicAdd(&hsh[d1[0]], 1u); atomicAdd(&hsh[d1[1]], 1u);
            atomicAdd(&hsh[d1[2]], 1u); atomicAdd(&hsh[d1[3]], 1u);
            atomicAdd(&hsh[d2[0]], 1u); atomicAdd(&hsh[d2[1]], 1u);
            atomicAdd(&hsh[d2[2]], 1u); atomicAdd(&hsh[d2[3]], 1u);
            atomicAdd(&hsh[d3[0]], 1u); atomicAdd(&hsh[d3[1]], 1u);
            atomicAdd(&hsh[d3[2]], 1u); atomicAdd(&hsh[d3[3]], 1u);
            atomicAdd(&hsh[d4[0]], 1u); atomicAdd(&hsh[d4[1]], 1u);
            atomicAdd(&hsh[d4[2]], 1u); atomicAdd(&hsh[d4[3]], 1u);
            atomicAdd(&hsh[d5[0]], 1u); atomicAdd(&hsh[d5[1]], 1u);
            atomicAdd(&hsh[d5[2]], 1u); atomicAdd(&hsh[d5[3]], 1u);
            atomicAdd(&hsh[d6[0]], 1u); atomicAdd(&hsh[d6[1]], 1u);
            atomicAdd(&hsh[d6[2]], 1u); atomicAdd(&hsh[d6[3]], 1u);
            atomicAdd(&hsh[d7[0]], 1u); atomicAdd(&hsh[d7[1]], 1u);
            atomicAdd(&hsh[d7[2]], 1u); atomicAdd(&hsh[d7[3]], 1u);
        }
        __syncthreads();
        // thread t owns counters [t*32, t*32+32)
        unsigned loc[32]; unsigned s = 0;
#pragma unroll
        for (int i = 0; i < 8; i++) {
            ui4 v = *(ui4*)&hsh[tid * 32 + i * 4];
            loc[i * 4] = v[0]; loc[i * 4 + 1] = v[1];
            loc[i * 4 + 2] = v[2]; loc[i * 4 + 3] = v[3];
            s += v[0] + v[1] + v[2] + v[3];
        }
        unsigned incl = s;                          // wave-inclusive scan
#pragma unroll
        for (int off = 1; off < 64; off <<= 1) {
            unsigned v = __shfl_up(incl, off);
            if ((tid & 63) >= (unsigned)off) incl += v;
        }
        if ((tid & 63) == 63) hsw[tid >> 6] = incl;
        __syncthreads();
        unsigned wp = 0;
        for (int w = 0; w < (tid >> 6); w++) wp += hsw[w];
        unsigned run = wp + incl - s;               // exclusive over all threads
        unsigned* c = cnt + (hb << 13) + tid * 32;
#pragma unroll
        for (int i = 0; i < 8; i++) {
            ui4 o;
            o[0] = run; run += loc[i * 4];
            o[1] = run; run += loc[i * 4 + 1];
            o[2] = run; run += loc[i * 4 + 2];
            o[3] = run; run += loc[i * 4 + 3];
            *(ui4*)&c[i * 4] = o;
        }
        return;
    }
    if (bid >= 4100) {   // weight repack tail: 480 blocks
        const int rb = bid - 4100;
        const int gid = rb * 256 + tid;
        if (rb < 96)       repack_one(w1a, w2a, w1n0, w2t0, 16, 32, gid);
        else if (rb < 288) repack_one(w1b, w2b, w1n1, w2t1, 128, 128, gid - 96 * 256);
        else               repack_one(w1c, w2c, w1n2, w2t2, 128, 128, gid - 288 * 256);
        return;
    }
    const int gid = (bid - 4) * 256 + tid;
    ui4 v = {KEY_INF, KEY_INF, KEY_INF, KEY_INF};
    ((ui4*)agg)[gid] = v;                               // 4096 blocks x 256
    if (bid < 516) {                                    // x0 prep: 131072 threads
        i4 x = ((const i4*)nf)[gid];
        us4 o;
        o[0] = f2b((float)x[0]); o[1] = f2b((float)x[1]);
        o[2] = f2b((float)x[2]); o[3] = f2b((float)x[3]);
        ((us4*)x0b)[gid] = o;
    }
}

// ---- per-node projection body: [Yd|Ys] = x @ [W1a|W1b] (+b1 on Yd half) ----
template<int KPAD, bool FROM_AGG>
__device__ __forceinline__ void node_body(
    int bid,
    const unsigned short* __restrict__ xin,
    unsigned* __restrict__ agg,
    const unsigned short* __restrict__ w1n,
    const float* __restrict__ bias1,
    unsigned short* __restrict__ Yd,
    unsigned short* __restrict__ Ys,
    char* smem)
{
    constexpr int ASTR = KPAD + 8;
    unsigned short* A  = (unsigned short*)smem;                       // 64*ASTR
    unsigned short* Yb = (unsigned short*)(smem + 64 * ASTR * 2);     // 64*264

    const int tid = threadIdx.x;
    const int wave = tid >> 6, lane = tid & 63, lq = lane >> 4, lm = lane & 15;
    const int tile = (bid & 7) * 64 + (bid >> 3);   // XCD-affine
    const int n0 = tile * 64;

    v8bf wf[4][KPAD / 32]; float b1v[4];
#pragma unroll
    for (int nt = 0; nt < 4; nt++) {
        const int col = wave * 64 + nt * 16 + lm;
#pragma unroll
        for (int ks = 0; ks < KPAD / 32; ks++)
            wf[nt][ks] = *(const v8bf*)&w1n[col * KPAD + ks * 32 + lq * 8];
        b1v[nt] = (col < 128) ? bias1[col] : 0.f;
    }

    // stage A (64 rows x KPAD)
    {
        const int row = tid >> 2, p = tid & 3;
        if (FROM_AGG) {
#pragma unroll
            for (int i = 0; i < 8; i++) {
                const int c = p + 4 * i;      // 32 ui4 chunks of 4 cols
                unsigned* ap = agg + ((size_t)(n0 + row)) * 128 + c * 4;
                ui4 k = *(ui4*)ap;
                ui4 inf = {KEY_INF, KEY_INF, KEY_INF, KEY_INF};
                *(ui4*)ap = inf;              // re-arm for next layer's atomics
                us4 o;
#pragma unroll
                for (int j = 0; j < 4; j++) {
                    float v = (k[j] == KEY_INF) ? 0.f : funkey(k[j]);
                    v = (v > 0.f) ? v : 0.01f * v;
                    o[j] = f2b(v);
                }
                *(us4*)&A[row * ASTR + c * 4] = o;
            }
        } else {
            us4 v = *(const us4*)(xin + ((size_t)(n0 + row)) * 16 + p * 4);
            *(us4*)&A[row * ASTR + p * 4] = v;
            us4 z = {0, 0, 0, 0};
            *(us4*)&A[row * ASTR + 16 + p * 4] = z;   // zero-pad K 16->32
        }
    }
    __syncthreads();

#pragma unroll
    for (int mt = 0; mt < 4; mt++) {
        v4f acc[4];
#pragma unroll
        for (int nt = 0; nt < 4; nt++) acc[nt] = v4f{0.f, 0.f, 0.f, 0.f};
#pragma unroll
        for (int ks = 0; ks < KPAD / 32; ks++) {
            v8bf a = *(const v8bf*)&A[(mt * 16 + lm) * ASTR + ks * 32 + lq * 8];
#pragma unroll
            for (int nt = 0; nt < 4; nt++)
                acc[nt] = __builtin_amdgcn_mfma_f32_16x16x32_bf16(a, wf[nt][ks], acc[nt], 0, 0, 0);
        }
#pragma unroll
        for (int nt = 0; nt < 4; nt++) {
            const int col = wave * 64 + nt * 16 + lm;
#pragma unroll
            for (int r = 0; r < 4; r++)
                Yb[(mt * 16 + lq * 4 + r) * 264 + col] = f2h(acc[nt][r] + b1v[nt]);
        }
    }
    __syncthreads();

    // coalesced copy-out
    const int bb = tile >> 7, nl0 = (tile & 127) * 64;
#pragma unroll
    for (int i = 0; i < 8; i++) {
        const int idx = tid + 256 * i;          // 2048 us8 chunks
        const int row = idx >> 5, c = idx & 31;
        us8 v = *(const us8*)&Yb[row * 264 + c * 8];
        const int col0 = c * 8;
        unsigned short* dp = (col0 < 128)
            ? (Yd + ((size_t)(bb * N_) + nl0 + row) * 128 + col0)
            : (Ys + ((size_t)(bb * N_) + nl0 + row) * 128 + (col0 - 128));
        *(us8*)dp = v;
    }
}

// conv2/3 node kernel
template<int KPAD>
__global__ __launch_bounds__(256, 3) void k_node(
    const unsigned short* __restrict__ xin, unsigned* __restrict__ agg,
    const unsigned short* __restrict__ w1n, const float* __restrict__ bias1,
    unsigned short* __restrict__ Yd, unsigned short* __restrict__ Ys)
{
    __shared__ __align__(16) char smem[64 * (KPAD + 8) * 2 + 64 * 264 * 2];
    node_body<KPAD, true>(blockIdx.x, xin, agg, w1n, bias1, Yd, Ys, smem);
}

// fused: blocks [0,2048) = edge scatter (after fused scan); [2048,2560) = conv1 node proj
__global__ __launch_bounds__(256, 3) void k_scat_node1(
    const int* __restrict__ ei, unsigned* __restrict__ wptr, int* __restrict__ perm,
    const unsigned short* __restrict__ x0b,
    const unsigned short* __restrict__ w1n, const float* __restrict__ bias1,
    unsigned short* __restrict__ Yd, unsigned short* __restrict__ Ys)
{
    __shared__ __align__(16) char smem[64 * 40 * 2 + 64 * 264 * 2];
    const int bid = blockIdx.x;
    if (bid < 2048) {   // scatter
        int gid = bid * 256 + threadIdx.x;              // B*E threads
        int b = gid >> 17, e = gid & (E_ - 1);
        int dst = ei[(b << 18) + E_ + e];
        unsigned pos = atomicAdd(&wptr[(b << 13) + dst], 1u);
        perm[(b << 17) + pos] = e;
        return;
    }
    node_body<32, false>(bid - 2048, x0b, (unsigned*)nullptr, w1n, bias1, Yd, Ys, smem);
}

// ---- fused edge kernel: FP16 packed-math gather + dbuf pipeline ---------
// gather Yd[dst]+Ys[src]+ea*wea -> leaky -> Hs (fp16, XOR-swizzled, stride
// 128) -> GEMM2 f16 MFMA -> carried register segmented min -> agg.
//
// STRUCTURE IS LOCKED — four failed structural probes:
//   R2 (8 blocks/CU, 32-edge tiles): FETCH ->514MB, 45->172us (chunk thrash)
//   R3 (reg-prefetch pipeline):      FETCH ->45MB,  45->50us
//   R4 (barrier-free per-lane gather): FETCH 895MB, 280us (dup loads)
//   R10 (512-thread blocks):         FETCH ->270MB, 46->115us — the (bid&7)
//        XCD map is calibrated to 256-thread dispatch; block-shape changes
//        silently break it.
// The 64-edge-tile / 512-edge-chunk / 1024x256 / 4-blocks-per-CU config is
// a narrow L2-locality optimum (FETCH 29MB ~= unique bytes). R9 proved
// k_edge is NOT fetch-bound (esrt tuples halved FETCH, dur unchanged) —
// it is latency-bound at <40% on all pipes; leave it.
//
// LAYOUT INVARIANT (R5 lesson — correctness): the carried segmented-min
// with interior PLAIN STORES requires each thread's edge walk to be a
// CONTIGUOUS run in sorted order. That holds ONLY with the run-major
// row->edge map below (Hs row mt*16+lq*4+r of tile jj <-> chunk-edge
// lq*128 + jj*16 + mt*4 + r). Change layout and aggregation policy
// together or not at all.
__global__ __launch_bounds__(256, 4) void k_edge(
    const unsigned short* __restrict__ Yd,    // fp16
    const unsigned short* __restrict__ Ys,    // fp16
    const int* __restrict__ ei,
    const float* __restrict__ eaf,
    const int* __restrict__ perm,
    const unsigned short* __restrict__ w2t,   // [128][128] fp16
    const float* __restrict__ weap,           // [128] = W1 row 2F (fp32)
    const float* __restrict__ bias2,
    unsigned* __restrict__ agg)
{
    __shared__ __align__(16) unsigned short Hs[2][64 * 128];   // fp16, swizzled
    __shared__ __align__(16) int      dstl[2][64];

    const int tid = threadIdx.x;
    const int wave = tid >> 6, lane = tid & 63, lq = lane >> 4, lm = lane & 15;

    hf8 w2f[2][4]; float b2v[2];
#pragma unroll
    for (int nt = 0; nt < 2; nt++) {
        const int col = wave * 32 + nt * 16 + lm;
#pragma unroll
        for (int ks = 0; ks < 4; ks++)
            w2f[nt][ks] = *(const hf8*)&w2t[col * 128 + ks * 32 + lq * 8];
        b2v[nt] = bias2[col];
    }

    // gather role: 4 threads/edge; arow = Hs row (0..63).
    // Run-major map: Hs row (mt*16 + lq*4 + r) holds chunk-edge
    // lq*128 + jj*16 + mt*4 + r  (contiguous 128-edge run per lq).
    const int arow = tid >> 2, p = tid & 3;
    const int lqg = (arow >> 2) & 3, mtg = arow >> 4, rg = arow & 3;
    const int sl  = lqg * 16 + mtg * 4 + rg;         // dstl slot
    const int se0 = lqg * 128 + mtg * 4 + rg;        // chunk-edge offset (+ jj*16)
    const int rsw = arow & 15;                       // store-side swizzle key

    // weal hoist: this thread's 4 loop-invariant W1-edge chunks (c = p+4i)
    hf8 wl0, wl1, wl2, wl3;
    {
        const float* wp = weap + p * 8;
#pragma unroll
        for (int u = 0; u < 8; u++) {
            wl0[u] = (_Float16)wp[u];
            wl1[u] = (_Float16)wp[32 + u];
            wl2[u] = (_Float16)wp[64 + u];
            wl3[u] = (_Float16)wp[96 + u];
        }
    }

    __syncthreads();   // prologue ordering margin (cheap, once per block)

    // one block = one chunk of 512 contiguous dst-sorted edges.
    // XCD-affine: XCD x gets 128 consecutive chunks (contiguous dst window).
    const int chunk = (blockIdx.x & 7) * 128 + (blockIdx.x >> 3);
    const int b = chunk >> 8;                        // 256 chunks per batch
    const int ebase = (b << 17) + (chunk & 255) * 512;

    const hf8 c01v = {(_Float16)0.01f, (_Float16)0.01f, (_Float16)0.01f, (_Float16)0.01f,
                      (_Float16)0.01f, (_Float16)0.01f, (_Float16)0.01f, (_Float16)0.01f};

    int e   = perm[ebase + se0];
    int src = ei[(b << 18) + e];
    int dst = ei[(b << 18) + E_ + e];
    float ea = eaf[(b << 17) + e];

    // prologue: gather tile 0 into buf 0
    {
        const hf8* ydp = (const hf8*)(Yd + ((size_t)(b * N_) + dst) * 128);
        const hf8* ysp = (const hf8*)(Ys + ((size_t)(b * N_) + src) * 128);
        if (p == 0) dstl[0][sl] = dst;
        const _Float16 eh = (_Float16)ea;
        const hf8 ea8 = {eh, eh, eh, eh, eh, eh, eh, eh};
        hf8 z;
        z = ydp[p] + ysp[p] + wl0 * ea8;
        z = __builtin_elementwise_max(z, z * c01v);   // leaky, v_pk_max_f16
        *(hf8*)&Hs[0][arow * 128 + ((p ^ rsw) * 8)] = z;
        z = ydp[p + 4] + ysp[p + 4] + wl1 * ea8;
        z = __builtin_elementwise_max(z, z * c01v);
        *(hf8*)&Hs[0][arow * 128 + (((p + 4) ^ rsw) * 8)] = z;
        z = ydp[p + 8] + ysp[p + 8] + wl2 * ea8;
        z = __builtin_elementwise_max(z, z * c01v);
        *(hf8*)&Hs[0][arow * 128 + (((p + 8) ^ rsw) * 8)] = z;
        z = ydp[p + 12] + ysp[p + 12] + wl3 * ea8;
        z = __builtin_elementwise_max(z, z * c01v);
        *(hf8*)&Hs[0][arow * 128 + (((p + 12) ^ rsw) * 8)] = z;
    }
    __syncthreads();

    // carried segmented-min state (per compute thread; run = 128 edges)
    const int col0 = wave * 32 + lm, col1 = col0 + 16;
    unsigned* aggb = agg + (size_t)(b * N_) * 128;
    float cur0 = 0.f, cur1 = 0.f; int curd = -1; bool fseg = true;

    for (int jj = 0; jj < 8; jj++) {
        const int buf = jj & 1;

        // ---- prefetch idx chain for tile jj+1 (drains under GEMM2) ----
        if (jj < 7) {
            e   = perm[ebase + se0 + (jj + 1) * 16];
            src = ei[(b << 18) + e];
            dst = ei[(b << 18) + E_ + e];
            ea  = eaf[(b << 17) + e];
        }

        // ---- GEMM2 (bias in acc init) + carried register segmented min ----
        {
#pragma unroll
            for (int mt = 0; mt < 4; mt++) {
                const int row = mt * 16 + lm;             // row & 15 == lm
                v4f acc0 = {b2v[0], b2v[0], b2v[0], b2v[0]};
                v4f acc1 = {b2v[1], b2v[1], b2v[1], b2v[1]};
#pragma unroll
                for (int ks = 0; ks < 4; ks++) {
                    hf8 a = *(const hf8*)&Hs[buf][row * 128 + (((ks * 4 + lq) ^ lm) * 8)];
                    acc0 = __builtin_amdgcn_mfma_f32_16x16x32_f16(a, w2f[0][ks], acc0, 0, 0, 0);
                    acc1 = __builtin_amdgcn_mfma_f32_16x16x32_f16(a, w2f[1][ks], acc1, 0, 0, 0);
                }
                i4 dv = *(const i4*)&dstl[buf][lq * 16 + mt * 4];
#pragma unroll
                for (int r = 0; r < 4; r++) {
                    const float v0 = acc0[r];
                    const float v1 = acc1[r];
                    const int d = dv[r];
                    if (d != curd) {
                        if (curd >= 0) {
                            unsigned* p0 = aggb + (size_t)curd * 128 + col0;
                            unsigned* p1 = aggb + (size_t)curd * 128 + col1;
                            if (fseg) {                    // may span into prev run
                                atomicMin(p0, fkey(cur0));
                                atomicMin(p1, fkey(cur1));
                            } else {                       // interior: exclusive owner
                                *p0 = fkey(cur0);
                                *p1 = fkey(cur1);
                            }
                            fseg = false;
                        }
                        curd = d; cur0 = v0; cur1 = v1;
                    } else {
                        cur0 = fminf(cur0, v0); cur1 = fminf(cur1, v1);
                    }
                }
            }
        }

        // ---- gather tile jj+1 into the other buffer ----
        if (jj < 7) {
            const hf8* ydp = (const hf8*)(Yd + ((size_t)(b * N_) + dst) * 128);
            const hf8* ysp = (const hf8*)(Ys + ((size_t)(b * N_) + src) * 128);
            if (p == 0) dstl[buf ^ 1][sl] = dst;
            const _Float16 eh = (_Float16)ea;
            const hf8 ea8 = {eh, eh, eh, eh, eh, eh, eh, eh};
            hf8 z;
            z = ydp[p] + ysp[p] + wl0 * ea8;
            z = __builtin_elementwise_max(z, z * c01v);
            *(hf8*)&Hs[buf ^ 1][arow * 128 + ((p ^ rsw) * 8)] = z;
            z = ydp[p + 4] + ysp[p + 4] + wl1 * ea8;
            z = __builtin_elementwise_max(z, z * c01v);
            *(hf8*)&Hs[buf ^ 1][arow * 128 + (((p + 4) ^ rsw) * 8)] = z;
            z = ydp[p + 8] + ysp[p + 8] + wl2 * ea8;
            z = __builtin_elementwise_max(z, z * c01v);
            *(hf8*)&Hs[buf ^ 1][arow * 128 + (((p + 8) ^ rsw) * 8)] = z;
            z = ydp[p + 12] + ysp[p + 12] + wl3 * ea8;
            z = __builtin_elementwise_max(z, z * c01v);
            *(hf8*)&Hs[buf ^ 1][arow * 128 + (((p + 12) ^ rsw) * 8)] = z;
        }
        __syncthreads();
    }

    // tail flush: touches run end -> may continue in next run/chunk: atomic
    atomicMin(aggb + (size_t)curd * 128 + col0, fkey(cur0));
    atomicMin(aggb + (size_t)curd * 128 + col1, fkey(cur1));
}

// ---- head: out = softplus([x0 | leaky(unkey(agg))] @ lin_w + lin_b) ----
__global__ __launch_bounds__(256, 4) void k_final(
    const unsigned short* __restrict__ x0b, const unsigned* __restrict__ agg,
    const float* __restrict__ lw, const float* __restrict__ lb,
    float* __restrict__ out) {
    __shared__ float w[144 * 8];
    __shared__ float bias8[8];
    __shared__ float xs[64 * 129];    // +1 pad: node-major, bank-spread
    const int tid = threadIdx.x;
    for (int i = tid; i < 1152; i += 256) w[i] = lw[i];
    if (tid < 8) bias8[tid] = lb[tid];
    const int n0 = blockIdx.x * 64;
#pragma unroll
    for (int i = 0; i < 8; i++) {
        const int idx = tid + 256 * i;
        const int row = idx >> 5, c = idx & 31;
        ui4 k = ((const ui4*)(agg + ((size_t)(n0 + row)) * 128))[c];
#pragma unroll
        for (int j = 0; j < 4; j++) {
            float v = (k[j] == KEY_INF) ? 0.f : funkey(k[j]);
            v = fmaxf(v, 0.01f * v);
            xs[row * 129 + c * 4 + j] = v;
        }
    }
    __syncthreads();
    const int node = tid >> 2, ap = (tid & 3) * 2;   // outputs ap, ap+1
    float a0 = bias8[ap], a1 = bias8[ap + 1];
    const unsigned short* x0 = x0b + (size_t)(n0 + node) * 16;
#pragma unroll
    for (int f = 0; f < 16; f++) {
        const float xv = b2f(x0[f]);
        a0 += xv * w[f * 8 + ap]; a1 += xv * w[f * 8 + ap + 1];
    }
    const float* xr = &xs[node * 129];
#pragma unroll 8
    for (int f = 0; f < 128; f++) {
        const float xv = xr[f];
        a0 += xv * w[(16 + f) * 8 + ap]; a1 += xv * w[(16 + f) * 8 + ap + 1];
    }
    v2f o;
    o[0] = fmaxf(a0, 0.f) + log1pf(expf(-fabsf(a0)));   // stable softplus
    o[1] = fmaxf(a1, 0.f) + log1pf(expf(-fabsf(a1)));
    *(v2f*)&out[(size_t)(n0 + node) * 8 + ap] = o;
}

extern "C" void kernel_launch(void* const* d_in, const int* in_sizes, int n_in,
                              void* d_out, int out_size, void* d_ws, size_t ws_size,
                              hipStream_t stream) {
    (void)in_sizes; (void)n_in; (void)out_size; (void)ws_size;
    const int* nf  = (const int*)d_in[0];
    const int* ei  = (const int*)d_in[1];
    const float* eaf = (const float*)d_in[2];
    const float* cw1[3] = {(const float*)d_in[3],  (const float*)d_in[7],  (const float*)d_in[11]};
    const float* cb1[3] = {(const float*)d_in[4],  (const float*)d_in[8],  (const float*)d_in[12]};
    const float* cw2[3] = {(const float*)d_in[5],  (const float*)d_in[9],  (const float*)d_in[13]};
    const float* cb2[3] = {(const float*)d_in[6],  (const float*)d_in[10], (const float*)d_in[14]};
    const float* lw = (const float*)d_in[15];
    const float* lb = (const float*)d_in[16];
    float* out = (float*)d_out;

    // workspace carve (all 256B aligned) — ~37.2 MB total
    size_t off = 0;
    auto carve = [&](size_t bytes) { void* p = (char*)d_ws + off; off += (bytes + 255) & ~(size_t)255; return p; };
    unsigned short* x0b  = (unsigned short*)carve((size_t)B_ * N_ * 16 * 2);    // 1 MB
    unsigned*       agg  = (unsigned*)carve((size_t)B_ * N_ * 128 * 4);         // 16.8 MB
    unsigned*       cnt  = (unsigned*)carve((size_t)B_ * N_ * 4);               // 128 KB
    int*            perm = (int*)carve((size_t)B_ * E_ * 4);                    // 2 MB
    unsigned short* Yd   = (unsigned short*)carve((size_t)B_ * N_ * 128 * 2);   // 8.4 MB (fp16)
    unsigned short* Ys   = (unsigned short*)carve((size_t)B_ * N_ * 128 * 2);   // 8.4 MB (fp16)
    unsigned short* w1n0 = (unsigned short*)carve(256 * 32 * 2);
    unsigned short* w2t0 = (unsigned short*)carve(128 * 128 * 2);
    unsigned short* w1n1 = (unsigned short*)carve(256 * 128 * 2);
    unsigned short* w2t1 = (unsigned short*)carve(128 * 128 * 2);
    unsigned short* w1n2 = (unsigned short*)carve(256 * 128 * 2);
    unsigned short* w2t2 = (unsigned short*)carve(128 * 128 * 2);

    // setup: fused per-batch hist+scan at bid 0..3 (start first, overlap fill)
    k_setup<<<4580, 256, 0, stream>>>(nf, x0b, cnt, agg, ei,
                                      cw1[0], cw2[0], cw1[1], cw2[1], cw1[2], cw2[2],
                                      w1n0, w2t0, w1n1, w2t1, w1n2, w2t2);

    // fused: edge scatter (2048 blocks) + conv1 node projection (512 blocks)
    k_scat_node1<<<2560, 256, 0, stream>>>(ei, cnt, perm, x0b, w1n0, cb1[0], Yd, Ys);
    k_edge<<<1024, 256, 0, stream>>>(Yd, Ys, ei, eaf, perm, w2t0, cw1[0] + 32 * 128, cb2[0], agg);

    // conv2: k_node reads conv1 agg + re-arms it
    k_node<128><<<512, 256, 0, stream>>>(x0b, agg, w1n1, cb1[1], Yd, Ys);
    k_edge<<<1024, 256, 0, stream>>>(Yd, Ys, ei, eaf, perm, w2t1, cw1[1] + 256 * 128, cb2[1], agg);

    // conv3
    k_node<128><<<512, 256, 0, stream>>>(x0b, agg, w1n2, cb1[2], Yd, Ys);
    k_edge<<<1024, 256, 0, stream>>>(Yd, Ys, ei, eaf, perm, w2t2, cw1[2] + 256 * 128, cb2[2], agg);

    k_final<<<512, 256, 0, stream>>>(x0b, agg, lw, lb, out);
}